// Round 1
// baseline (245.576 us; speedup 1.0000x reference)
//
#include <hip/hip_runtime.h>
#include <hip/hip_bf16.h>

#define U_DIM 1024
#define H_DIM 4096
#define N_DIM 8192   // 2H
#define K_DIM 4096   // = H

#define BM 128
#define BN 128
#define BK 32

typedef __attribute__((ext_vector_type(8))) short bf16x8;
typedef __attribute__((ext_vector_type(4))) float f32x4;

__device__ inline unsigned short f2bf(float f) {
  union { float f; unsigned u; } a; a.f = f;
  unsigned r = a.u + 0x7fffu + ((a.u >> 16) & 1u);  // RNE
  return (unsigned short)(r >> 16);
}

__device__ inline void gload_lds16(const void* g, void* l) {
  __builtin_amdgcn_global_load_lds(
      (const __attribute__((address_space(1))) unsigned*)(g),
      (__attribute__((address_space(3))) unsigned*)(l), 16, 0, 0);
}

// ---------------- x fp32 -> bf16 ----------------
__global__ __launch_bounds__(256) void convert_x_kernel(
    const float* __restrict__ x, unsigned short* __restrict__ xb) {
  size_t i = (size_t)blockIdx.x * 256 + threadIdx.x;   // each handles 4 elems
  float4 v = ((const float4*)x)[i];
  ushort4 o;
  o.x = f2bf(v.x); o.y = f2bf(v.y); o.z = f2bf(v.z); o.w = f2bf(v.w);
  ((ushort4*)xb)[i] = o;
}

// ---------------- ssm_proj [K][N] fp32 -> Bt [N][K] bf16 ----------------
__global__ __launch_bounds__(256) void transpose_b_kernel(
    const float* __restrict__ B, unsigned short* __restrict__ Bt) {
  __shared__ float tile[64][65];
  const int kt = blockIdx.x % (K_DIM / 64);   // 64 k-tiles
  const int nt = blockIdx.x / (K_DIM / 64);   // 128 n-tiles
  const int k0 = kt * 64, n0 = nt * 64;
  const int tid = threadIdx.x;
  const int cr = tid >> 4;          // 0..15
  const int cc = (tid & 15) * 4;    // 0..60 step 4

#pragma unroll
  for (int it = 0; it < 4; ++it) {
    int r = it * 16 + cr;           // local k row
    float4 v = *(const float4*)(&B[(size_t)(k0 + r) * N_DIM + n0 + cc]);
    tile[r][cc + 0] = v.x; tile[r][cc + 1] = v.y;
    tile[r][cc + 2] = v.z; tile[r][cc + 3] = v.w;
  }
  __syncthreads();
#pragma unroll
  for (int it = 0; it < 4; ++it) {
    int rn = it * 16 + cr;          // local n row
    ushort4 o;
    o.x = f2bf(tile[cc + 0][rn]);
    o.y = f2bf(tile[cc + 1][rn]);
    o.z = f2bf(tile[cc + 2][rn]);
    o.w = f2bf(tile[cc + 3][rn]);
    *(ushort4*)(&Bt[(size_t)(n0 + rn) * K_DIM + k0 + cc]) = o;
  }
}

// ---------------- bf16 MFMA GEMM (m97 structure) + fused conv epilogue ----------------
__global__ __launch_bounds__(256) void gemm_conv_kernel(
    const unsigned short* __restrict__ Abf,   // [U][K] bf16
    const unsigned short* __restrict__ Btbf,  // [N][K] bf16
    const float* __restrict__ conv_states,    // [4][U][N]
    const float* __restrict__ conv_wts,       // [4][N]
    const float* __restrict__ conv_bias,      // [N]
    float* __restrict__ out,                  // [U][N]
    float* __restrict__ ns3)                  // [U][N] (= new_states[3])
{
  __shared__ unsigned short smem[BM * BK + BN * BK];  // 8KB A + 8KB B
  unsigned short* sA = smem;
  unsigned short* sB = smem + BM * BK;

  const int bid  = blockIdx.x;
  const int brow = bid % (U_DIM / BM);   // 8, fastest -> consecutive blocks share B panel
  const int bcol = bid / (U_DIM / BM);   // 64
  const int tid  = threadIdx.x;
  const int lane = tid & 63;
  const int wid  = tid >> 6;
  const int wr = wid >> 1, wc = wid & 1;

  f32x4 acc[4][4];
#pragma unroll
  for (int m = 0; m < 4; ++m)
#pragma unroll
    for (int n = 0; n < 4; ++n)
#pragma unroll
      for (int r = 0; r < 4; ++r) acc[m][n][r] = 0.0f;

  const int srow  = lane >> 2;   // row within a 16-row staging issue
  const int sslot = lane & 3;    // 16B slot within 64B row
  const int fs    = lane >> 4;   // k-slot for fragment reads
  const int fra   = wr * 64 + (lane & 15);  // fragment A row base
  const int frb   = wc * 64 + (lane & 15);  // fragment B row base

  for (int k0 = 0; k0 < K_DIM; k0 += BK) {
    __syncthreads();
    // stage A tile [BM][BK] and B tile [BN][BK], linear LDS, 16B/lane
#pragma unroll
    for (int i = 0; i < 2; ++i) {
      int rloc = (wid * 2 + i) * 16 + srow;
      const unsigned short* gA =
          Abf + (size_t)(brow * BM + rloc) * K_DIM + k0 + sslot * 8;
      gload_lds16(gA, (char*)sA + (wid * 2 + i) * 1024);
      const unsigned short* gB =
          Btbf + (size_t)(bcol * BN + rloc) * K_DIM + k0 + sslot * 8;
      gload_lds16(gB, (char*)sB + (wid * 2 + i) * 1024);
    }
    __syncthreads();

    bf16x8 af[4], bf[4];
#pragma unroll
    for (int m = 0; m < 4; ++m)
      af[m] = *(const bf16x8*)((const char*)sA + (fra + m * 16) * (BK * 2) + fs * 16);
#pragma unroll
    for (int n = 0; n < 4; ++n)
      bf[n] = *(const bf16x8*)((const char*)sB + (frb + n * 16) * (BK * 2) + fs * 16);

#pragma unroll
    for (int m = 0; m < 4; ++m)
#pragma unroll
      for (int n = 0; n < 4; ++n)
        acc[m][n] = __builtin_amdgcn_mfma_f32_16x16x32_bf16(af[m], bf[n], acc[m][n], 0, 0, 0);
  }

  // epilogue: out = w0*cs1 + w1*cs2 + w2*cs3 + w3*xp + bias ; ns3 = xp
  const float* cs1 = conv_states + (size_t)1 * U_DIM * N_DIM;
  const float* cs2 = conv_states + (size_t)2 * U_DIM * N_DIM;
  const float* cs3 = conv_states + (size_t)3 * U_DIM * N_DIM;

#pragma unroll
  for (int n = 0; n < 4; ++n) {
    const int d = bcol * BN + wc * 64 + n * 16 + (lane & 15);
    const float w0 = conv_wts[d];
    const float w1 = conv_wts[N_DIM + d];
    const float w2 = conv_wts[2 * N_DIM + d];
    const float w3 = conv_wts[3 * N_DIM + d];
    const float bs = conv_bias[d];
#pragma unroll
    for (int m = 0; m < 4; ++m) {
#pragma unroll
      for (int r = 0; r < 4; ++r) {
        const int u = brow * BM + wr * 64 + m * 16 + fs * 4 + r;
        const size_t idx = (size_t)u * N_DIM + d;
        const float xpv = acc[m][n][r];
        out[idx] = w0 * cs1[idx] + w1 * cs2[idx] + w2 * cs3[idx] + w3 * xpv + bs;
        ns3[idx] = xpv;
      }
    }
  }
}

extern "C" void kernel_launch(void* const* d_in, const int* in_sizes, int n_in,
                              void* d_out, int out_size, void* d_ws, size_t ws_size,
                              hipStream_t stream) {
  (void)in_sizes; (void)n_in; (void)out_size; (void)d_ws; (void)ws_size;
  const float* x           = (const float*)d_in[0];
  const float* ssm_proj    = (const float*)d_in[1];
  const float* conv_states = (const float*)d_in[2];
  const float* conv_wts    = (const float*)d_in[3];
  const float* conv_bias   = (const float*)d_in[4];
  float* outp = (float*)d_out;

  const size_t OUT_ELEMS = (size_t)U_DIM * N_DIM;        // 8M floats
  float* ns  = outp + OUT_ELEMS;                         // new_states[0] base
  float* ns3 = ns + 3 * OUT_ELEMS;                       // new_states[3]

  // Scratch lives inside d_out's new_states[0:2] region (floats [8M..26M)),
  // which is overwritten by the final memcpy AFTER the GEMM consumed it.
  unsigned short* Btbf = (unsigned short*)ns;                    // 64MB: floats [8M..24M)
  unsigned short* xbf  = (unsigned short*)(ns + 2 * OUT_ELEMS);  // 8MB : floats [24M..26M)

  convert_x_kernel<<<(U_DIM * H_DIM / 4) / 256, 256, 0, stream>>>(x, xbf);
  transpose_b_kernel<<<(N_DIM / 64) * (K_DIM / 64), 256, 0, stream>>>(ssm_proj, Btbf);
  gemm_conv_kernel<<<(U_DIM / BM) * (N_DIM / BN), 256, 0, stream>>>(
      xbf, Btbf, conv_states, conv_wts, conv_bias, outp, ns3);
  // new_states[0:3] = conv_states[1:4] — both contiguous, one d2d copy
  hipMemcpyAsync(ns, conv_states + OUT_ELEMS, 3 * OUT_ELEMS * sizeof(float),
                 hipMemcpyDeviceToDevice, stream);
}